// Round 5
// baseline (18906.850 us; speedup 1.0000x reference)
//
#include <hip/hip_runtime.h>
#include <hip/hip_bf16.h>

// Problem dims (fixed by reference). All global I/O is fp32.
#define BATCH 1024
#define DLAT  512
#define HHID  1024
#define TPTS  64
#define BD    (BATCH * DLAT)     // 524288

#define MROWS 16                 // batch rows per block
#define NBLK  (BATCH / MROWS)    // 64 persistent blocks
#define NTHR  512                // 8 waves

typedef __attribute__((ext_vector_type(8))) short short8;  // 8 bf16 (4 VGPRs)
typedef __attribute__((ext_vector_type(4))) float f32x4;   // MFMA C/D frag

__device__ __forceinline__ short f2bf(float x) {
    __hip_bfloat16 h = __float2bfloat16(x);
    return __builtin_bit_cast(short, h);
}
__device__ __forceinline__ float fast_tanh(float x) {
    x = fminf(9.f, fmaxf(-9.f, x));
    const float e = __expf(2.f * x);
    return (e - 1.f) / (e + 1.f);
}

// async 16B/lane global->LDS DMA. LDS dest is wave-uniform base; lane i's
// 16B lands at base + i*16 (m97/m104 semantics). Global addr is per-lane.
__device__ __forceinline__ void ld_lds16(void* lds, const void* g) {
    __builtin_amdgcn_global_load_lds(
        (const __attribute__((address_space(1))) unsigned int*)g,
        (__attribute__((address_space(3))) unsigned int*)lds, 16, 0, 0);
}
// s_waitcnt vmcnt(N), lgkmcnt/expcnt unlimited (gfx9 encoding, N<16)
#define WAITVM(N) __builtin_amdgcn_s_waitcnt(0x0F70 | (N))

// mfma_f32_16x16x32_bf16 layouts (m89/m120-verified):
//   A[m = lane&15][k = (lane>>4)*8 + j],  B[k = (lane>>4)*8 + j][n = lane&15]
//   C/D: col = lane&15, row = (lane>>4)*4 + reg
__device__ __forceinline__ int frag_idx(int r, int n) {
    return (((n >> 5) * 64) + (r | (((n >> 3) & 3) << 4))) * 8 + (n & 7);
}

// ---------------------------------------------------------------------------
// init_pack: fp32 W1/W2 -> bf16 MFMA B-fragment order; traj[0] = z0 (fp32).
//   W1p: [K1/32=16][N1/16=64][lane 64][j 8]   (element W1[k][n], k=D, n=H)
//   W2p: [K2/32=32][N2/16=32][lane 64][j 8]   (element W2[k][n], k=H, n=D)
// ---------------------------------------------------------------------------
__global__ __launch_bounds__(256) void init_pack(const float* __restrict__ z0,
                                                 const float* __restrict__ W1,
                                                 const float* __restrict__ W2,
                                                 short* __restrict__ W1p,
                                                 short* __restrict__ W2p,
                                                 float* __restrict__ traj)
{
    const int g = blockIdx.x * 256 + threadIdx.x;   // 0..65535

    {   // W1 group: g = ((kt*64 + nt)*64 + l)
        const int kt = g >> 12, rem = g & 4095, nt = rem >> 6, l = rem & 63;
        const int k0 = kt * 32 + (l >> 4) * 8;
        const int n  = nt * 16 + (l & 15);
        short8 v;
#pragma unroll
        for (int j = 0; j < 8; ++j) v[j] = f2bf(W1[(size_t)(k0 + j) * HHID + n]);
        *(short8*)&W1p[(size_t)g * 8] = v;
    }
    {   // W2 group: g = ((kt*32 + nt)*64 + l)
        const int kt = g >> 11, rem = g & 2047, nt = rem >> 6, l = rem & 63;
        const int k0 = kt * 32 + (l >> 4) * 8;
        const int n  = nt * 16 + (l & 15);
        short8 v;
#pragma unroll
        for (int j = 0; j < 8; ++j) v[j] = f2bf(W2[(size_t)(k0 + j) * DLAT + n]);
        *(short8*)&W2p[(size_t)g * 8] = v;
    }
    const float4* s = (const float4*)z0;
    float4*       d = (float4*)traj;
    d[(size_t)g * 2 + 0] = s[(size_t)g * 2 + 0];
    d[(size_t)g * 2 + 1] = s[(size_t)g * 2 + 1];
}

// ---------------------------------------------------------------------------
// Persistent ODE kernel: 64 blocks x 16 batch rows, all 63 RK4 steps.
// Weights stream L2 -> LDS via async DMA (per-wave 2-slot ring, 4KB chunks),
// MFMA B-frags read from LDS. z state exact fp32 in registers.
// LDS: Abuf 16K + HL 32K + Wst 64K + biases 6K = 118 KB -> 1 block/CU.
// ---------------------------------------------------------------------------
__global__ __launch_bounds__(NTHR, 1) void ode_persistent(
    const float* __restrict__ z0, const float* __restrict__ t,
    const short* __restrict__ W1p, const short* __restrict__ W2p,
    const float* __restrict__ b1, const float* __restrict__ b2,
    float* __restrict__ traj)
{
    __shared__ __align__(16) short Abuf[16 * 64 * 8];      // 16 KB
    __shared__ __align__(16) short HL[32 * 64 * 8];        // 32 KB
    __shared__ __align__(16) short Wst[8 * 2 * 4 * 64 * 8];// 64 KB ring
    __shared__ float b1L[HHID];                            //  4 KB
    __shared__ float b2L[DLAT];                            //  2 KB

    const int tid  = threadIdx.x;
    const int lane = tid & 63;
    const int wv   = tid >> 6;       // 0..7
    const int q    = lane >> 4;
    const int col  = lane & 15;
    const int rb   = blockIdx.x * MROWS;

    // short-index of ring slice (wv, slot, j), excluding lane*8 term
    auto widx = [&](int slot, int j) {
        return (((wv * 2 + slot) * 4 + j) * 64) * 8;
    };
    // issue one 4KB chunk: GEMM1 chunk (kt,h) covers nt = wv*8 + h*4 + j
    auto issue_g1 = [&](int kt, int h, int slot) {
#pragma unroll
        for (int j = 0; j < 4; ++j)
            ld_lds16(&Wst[widx(slot, j)],
                     W1p + (((size_t)kt * 64 + wv * 8 + h * 4 + j) * 64 + lane) * 8);
    };
    // GEMM2 chunk kt2 covers nt2 = wv*4 + j
    auto issue_g2 = [&](int kt2, int slot) {
#pragma unroll
        for (int j = 0; j < 4; ++j)
            ld_lds16(&Wst[widx(slot, j)],
                     W2p + (((size_t)kt2 * 32 + wv * 4 + j) * 64 + lane) * 8);
    };

    for (int i = tid; i < HHID; i += NTHR) b1L[i] = b1[i];
    for (int i = tid; i < DLAT; i += NTHR) b2L[i] = b2[i];

    float zreg[4][4];   // exact fp32 integration state
    float kacc[4][4];   // RK4 k-accumulator

#pragma unroll
    for (int tt = 0; tt < 4; ++tt) {
        const int n = (wv * 4 + tt) * 16 + col;
#pragma unroll
        for (int reg = 0; reg < 4; ++reg) {
            const int r  = q * 4 + reg;
            const float zv = z0[(size_t)(rb + r) * DLAT + n];
            zreg[tt][reg] = zv;
            Abuf[frag_idx(r, n)] = f2bf(zv);
        }
    }
    __syncthreads();

    for (int step = 0; step < TPTS - 1; ++step) {
        const float dt = t[step + 1] - t[step];

        for (int stage = 0; stage < 4; ++stage) {
            // ================= GEMM1: H = tanh(A @ W1 + b1) =================
            {
                f32x4 hacc[8];
#pragma unroll
                for (int c = 0; c < 8; ++c) hacc[c] = (f32x4){0.f, 0.f, 0.f, 0.f};

                issue_g1(0, 0, 0);                    // prime chunk 0
                short8 a0;
#pragma unroll
                for (int c = 0; c < 32; ++c) {        // 32 half-kt chunks
                    const int kt = c >> 1, h = c & 1;
                    const int cn = (c < 31) ? c + 1 : 31;   // clamped (dup ok)
                    issue_g1(cn >> 1, cn & 1, (c + 1) & 1);
                    WAITVM(4);                        // chunk c landed
                    if (h == 0) a0 = *(const short8*)&Abuf[(kt * 64 + lane) * 8];
#pragma unroll
                    for (int j = 0; j < 4; ++j) {
                        const short8 b = *(const short8*)&Wst[widx(c & 1, j) + lane * 8];
                        hacc[h * 4 + j] = __builtin_amdgcn_mfma_f32_16x16x32_bf16(
                            a0, b, hacc[h * 4 + j], 0, 0, 0);
                    }
                }
                // epilogue: bias + tanh -> HL in GEMM2-A fragment order
#pragma unroll
                for (int c = 0; c < 8; ++c) {
                    const int Hc   = (wv * 8 + c) * 16 + col;
                    const float bb = b1L[Hc];
#pragma unroll
                    for (int reg = 0; reg < 4; ++reg) {
                        const int r = q * 4 + reg;
                        HL[frag_idx(r, Hc)] = f2bf(fast_tanh(hacc[c][reg] + bb));
                    }
                }
            }
            __syncthreads();

            // ============ GEMM2: kv = H @ W2 + b2 ; RK4 stage update =========
            {
                f32x4 kv4[4];
#pragma unroll
                for (int c = 0; c < 4; ++c) kv4[c] = (f32x4){0.f, 0.f, 0.f, 0.f};

                issue_g2(0, 0);                       // prime chunk 0
#pragma unroll
                for (int c = 0; c < 32; ++c) {        // 32 kt2 chunks
                    const int cn = (c < 31) ? c + 1 : 31;
                    issue_g2(cn, (c + 1) & 1);
                    WAITVM(4);
                    const short8 a0 = *(const short8*)&HL[(c * 64 + lane) * 8];
#pragma unroll
                    for (int j = 0; j < 4; ++j) {
                        const short8 b = *(const short8*)&Wst[widx(c & 1, j) + lane * 8];
                        kv4[j] = __builtin_amdgcn_mfma_f32_16x16x32_bf16(
                            a0, b, kv4[j], 0, 0, 0);
                    }
                }
                // epilogue: RK4 stage update (registers) + next A into Abuf
#pragma unroll
                for (int tt = 0; tt < 4; ++tt) {
                    const int n    = (wv * 4 + tt) * 16 + col;
                    const float bb = b2L[n];
#pragma unroll
                    for (int reg = 0; reg < 4; ++reg) {
                        const int r  = q * 4 + reg;
                        const float kv = kv4[tt][reg] + bb;
                        float znext;
                        if (stage == 0) {
                            kacc[tt][reg] = kv;
                            znext = zreg[tt][reg] + 0.5f * dt * kv;
                        } else if (stage == 1) {
                            kacc[tt][reg] += 2.f * kv;
                            znext = zreg[tt][reg] + 0.5f * dt * kv;
                        } else if (stage == 2) {
                            kacc[tt][reg] += 2.f * kv;
                            znext = zreg[tt][reg] + dt * kv;
                        } else {
                            zreg[tt][reg] += (dt * (1.f / 6.f)) * (kacc[tt][reg] + kv);
                            znext = zreg[tt][reg];
                        }
                        Abuf[frag_idx(r, n)] = f2bf(znext);
                    }
                }
            }
            __syncthreads();
        }

        // traj[step+1] = exact fp32 z straight from registers
#pragma unroll
        for (int tt = 0; tt < 4; ++tt) {
            const int n = (wv * 4 + tt) * 16 + col;
#pragma unroll
            for (int reg = 0; reg < 4; ++reg) {
                const int r = q * 4 + reg;
                traj[(size_t)(step + 1) * BD + (size_t)(rb + r) * DLAT + n] =
                    zreg[tt][reg];
            }
        }
    }
}

// ---------------------------------------------------------------------------
extern "C" void kernel_launch(void* const* d_in, const int* in_sizes, int n_in,
                              void* d_out, int out_size, void* d_ws, size_t ws_size,
                              hipStream_t stream)
{
    (void)in_sizes; (void)n_in; (void)out_size; (void)ws_size;

    const float* z0 = (const float*)d_in[0];
    const float* t  = (const float*)d_in[1];
    const float* W1 = (const float*)d_in[2];
    const float* b1 = (const float*)d_in[3];
    const float* W2 = (const float*)d_in[4];
    const float* b2 = (const float*)d_in[5];
    float*       traj = (float*)d_out;

    short* W1p = (short*)d_ws;           // 1 MB packed bf16
    short* W2p = W1p + (size_t)BD;       // 1 MB packed bf16

    init_pack<<<256, 256, 0, stream>>>(z0, W1, W2, W1p, W2p, traj);
    ode_persistent<<<NBLK, NTHR, 0, stream>>>(z0, t, W1p, W2p, b1, b2, traj);
}